// Round 3
// baseline (2330.450 us; speedup 1.0000x reference)
//
#include <hip/hip_runtime.h>

typedef __bf16 bf16x8 __attribute__((ext_vector_type(8)));
typedef float  f32x4  __attribute__((ext_vector_type(4)));

#define GLOAD_LDS16(gp, lp) \
  __builtin_amdgcn_global_load_lds((const __attribute__((address_space(1))) void*)(gp), \
                                   (__attribute__((address_space(3))) void*)(lp), 16, 0, 0)

__device__ __forceinline__ unsigned short f2bf(float f) {
  unsigned u = __float_as_uint(f);
  u += 0x7fffu + ((u >> 16) & 1u);
  return (unsigned short)(u >> 16);
}
__device__ __forceinline__ float bf2f(unsigned short h) {
  return __uint_as_float(((unsigned)h) << 16);
}
__device__ __forceinline__ void bf8_to_f32(const unsigned short* src, float* dst) {
  uint4 r = *(const uint4*)src;
  unsigned v0 = r.x, v1 = r.y, v2 = r.z, v3 = r.w;
  dst[0] = __uint_as_float(v0 << 16); dst[1] = __uint_as_float(v0 & 0xffff0000u);
  dst[2] = __uint_as_float(v1 << 16); dst[3] = __uint_as_float(v1 & 0xffff0000u);
  dst[4] = __uint_as_float(v2 << 16); dst[5] = __uint_as_float(v2 & 0xffff0000u);
  dst[6] = __uint_as_float(v3 << 16); dst[7] = __uint_as_float(v3 & 0xffff0000u);
}

__device__ __forceinline__ void store_out(unsigned short* C, size_t idx, float v) {
  C[idx] = f2bf(v);
}
__device__ __forceinline__ void store_out(float* C, size_t idx, float v) {
  C[idx] = v;
}

// ---------------- RMSNorm (prenorm) #1: fp32 hidden + fp32 residual ----------------
__global__ __launch_bounds__(256) void rmsnorm1_kernel(
    const float* __restrict__ hid, const float* __restrict__ resin,
    const float* __restrict__ w, float* __restrict__ resout,
    unsigned short* __restrict__ hout)
{
  const int row = blockIdx.x, t = threadIdx.x;
  const size_t base = (size_t)row * 1024;
  float4 h = ((const float4*)(hid + base))[t];
  float4 r = ((const float4*)(resin + base))[t];
  float4 s; s.x = h.x + r.x; s.y = h.y + r.y; s.z = h.z + r.z; s.w = h.w + r.w;
  float ss = s.x*s.x + s.y*s.y + s.z*s.z + s.w*s.w;
  #pragma unroll
  for (int off = 32; off; off >>= 1) ss += __shfl_down(ss, off, 64);
  __shared__ float red[4];
  if ((t & 63) == 0) red[t >> 6] = ss;
  __syncthreads();
  float tot = red[0] + red[1] + red[2] + red[3];
  float sc = rsqrtf(tot * (1.0f/1024.0f) + 1e-5f);
  ((float4*)(resout + base))[t] = s;
  float4 wv = ((const float4*)w)[t];
  ushort4 o = make_ushort4(f2bf(s.x*sc*wv.x), f2bf(s.y*sc*wv.y),
                           f2bf(s.z*sc*wv.z), f2bf(s.w*sc*wv.w));
  ((ushort4*)(hout + base))[t] = o;
}

// ---------------- RMSNorm (prenorm) #2: bf16 mamba_out + fp32 res1 ----------------
// res output now written as FP32 (reference output dtype).
__global__ __launch_bounds__(256) void rmsnorm2_kernel(
    const unsigned short* __restrict__ mo, const float* __restrict__ res1,
    const float* __restrict__ w, float* __restrict__ res_out,
    unsigned short* __restrict__ h2)
{
  const int row = blockIdx.x, t = threadIdx.x;
  const size_t base = (size_t)row * 1024;
  float4 r = ((const float4*)(res1 + base))[t];
  ushort4 m = ((const ushort4*)(mo + base))[t];
  float4 s; s.x = r.x + bf2f(m.x); s.y = r.y + bf2f(m.y);
            s.z = r.z + bf2f(m.z); s.w = r.w + bf2f(m.w);
  float ss = s.x*s.x + s.y*s.y + s.z*s.z + s.w*s.w;
  #pragma unroll
  for (int off = 32; off; off >>= 1) ss += __shfl_down(ss, off, 64);
  __shared__ float red[4];
  if ((t & 63) == 0) red[t >> 6] = ss;
  __syncthreads();
  float tot = red[0] + red[1] + red[2] + red[3];
  float sc = rsqrtf(tot * (1.0f/1024.0f) + 1e-5f);
  ((float4*)(res_out + base))[t] = s;
  float4 wv = ((const float4*)w)[t];
  ((ushort4*)(h2 + base))[t] = make_ushort4(f2bf(s.x*sc*wv.x), f2bf(s.y*sc*wv.y),
                                            f2bf(s.z*sc*wv.z), f2bf(s.w*sc*wv.w));
}

// ---------------- fp32 -> bf16 weight cast with row padding ----------------
__global__ __launch_bounds__(256) void cast_w(
    const float* __restrict__ src, unsigned short* __restrict__ dst,
    int rows, int cols, int prows)
{
  size_t i4 = ((size_t)blockIdx.x * 256 + threadIdx.x) * 4;
  size_t total = (size_t)prows * cols;
  if (i4 >= total) return;
  int r = (int)(i4 / cols);
  ushort4 o;
  if (r < rows) {
    float4 v = *(const float4*)(src + i4);
    o = make_ushort4(f2bf(v.x), f2bf(v.y), f2bf(v.z), f2bf(v.w));
  } else {
    o = make_ushort4(0, 0, 0, 0);
  }
  *(ushort4*)(dst + i4) = o;
}

// ---------------- bf16 GEMM:  C[m,n] = sum_k A[m,k] * W[n,k]  (NT) ----------------
// 128x128 tile, BK=32, 256 threads (4 waves in 2x2), mfma_f32_16x16x32_bf16,
// global_load_lds width-16 staging (R1 vs R2 bit-identical => staging verified).
template <typename OutT>
__global__ __launch_bounds__(256) void gemm_bt(
    const unsigned short* __restrict__ A, const unsigned short* __restrict__ W,
    OutT* __restrict__ C, int M, int N, int K, int ldc)
{
  __shared__ unsigned short As[128 * 32];
  __shared__ unsigned short Bs[128 * 32];
  const int tid = threadIdx.x;
  const int wave = tid >> 6, lane = tid & 63;
  const int m0 = blockIdx.y << 7, n0 = blockIdx.x << 7;
  const int lr = lane >> 2;              // row within 16-row staging group
  const int lk = (lane & 3) << 3;        // k-chunk (8 bf16 = 16 B)
  const int wm = (wave >> 1) << 6, wn = (wave & 1) << 6;
  const int fr = lane & 15, fq = lane >> 4;

  f32x4 acc[4][4];
  #pragma unroll
  for (int i = 0; i < 4; i++)
    #pragma unroll
    for (int j = 0; j < 4; j++)
      #pragma unroll
      for (int r = 0; r < 4; r++) acc[i][j][r] = 0.0f;

  const unsigned short* Abase = A + (size_t)(m0 + wave*32 + lr) * K + lk;
  const unsigned short* Wbase = W + (size_t)(n0 + wave*32 + lr) * K + lk;
  const size_t rstep = (size_t)16 * K;
  unsigned short* AsW = As + (wave*32) * 32;
  unsigned short* BsW = Bs + (wave*32) * 32;

  for (int k0 = 0; k0 < K; k0 += 32) {
    GLOAD_LDS16(Abase + k0,         AsW);
    GLOAD_LDS16(Abase + k0 + rstep, AsW + 16*32);
    GLOAD_LDS16(Wbase + k0,         BsW);
    GLOAD_LDS16(Wbase + k0 + rstep, BsW + 16*32);
    __syncthreads();
    bf16x8 af[4], bfv[4];
    #pragma unroll
    for (int i = 0; i < 4; i++) {
      af[i]  = *(const bf16x8*)(As + (wm + i*16 + fr) * 32 + fq*8);
      bfv[i] = *(const bf16x8*)(Bs + (wn + i*16 + fr) * 32 + fq*8);
    }
    #pragma unroll
    for (int i = 0; i < 4; i++)
      #pragma unroll
      for (int j = 0; j < 4; j++)
        acc[i][j] = __builtin_amdgcn_mfma_f32_16x16x32_bf16(af[i], bfv[j], acc[i][j], 0, 0, 0);
    __syncthreads();
  }

  #pragma unroll
  for (int i = 0; i < 4; i++)
    #pragma unroll
    for (int j = 0; j < 4; j++)
      #pragma unroll
      for (int r = 0; r < 4; r++) {
        int gm = m0 + wm + i*16 + fq*4 + r;
        int gn = n0 + wn + j*16 + fr;
        store_out(C, (size_t)gm * ldc + gn, acc[i][j][r]);
      }
}

// ---------------- causal depthwise conv (K=4) + silu, and dt/dA precompute ----------------
__global__ __launch_bounds__(256) void conv_dt_kernel(
    const unsigned short* __restrict__ zx, const float* __restrict__ conv_w,
    const float* __restrict__ conv_b, const float* __restrict__ dt_bias,
    const float* __restrict__ A_log, unsigned short* __restrict__ conv_out,
    float* __restrict__ dtv, float* __restrict__ dAv)
{
  size_t idx = (size_t)blockIdx.x * 256 + threadIdx.x;
  if (idx >= (size_t)8192 * 2336) return;
  int c = (int)(idx % 2336);
  int row = (int)(idx / 2336);
  int l = row & 4095;
  if (c < 2304) {
    float acc = conv_b[c];
    const float* wp = conv_w + c * 4;
    #pragma unroll
    for (int j = 0; j < 4; j++) {
      int ls = l - 3 + j;
      if (ls >= 0) acc += bf2f(zx[(size_t)(row - 3 + j) * 4480 + 2048 + c]) * wp[j];
    }
    float s = acc / (1.0f + expf(-acc));
    conv_out[(size_t)row * 2304 + c] = f2bf(s);
  } else {
    int h = c - 2304;
    float draw = bf2f(zx[(size_t)row * 4480 + 4352 + h]) + dt_bias[h];
    float sp = (draw > 20.0f) ? draw : log1pf(expf(draw));
    float Ah = -expf(A_log[h]);
    dtv[(size_t)row * 32 + h] = sp;
    dAv[(size_t)row * 32 + h] = expf(sp * Ah);
  }
}

// ---------------- selective scan: one wg per (b, h, p-octant) ----------------
__global__ __launch_bounds__(128) void scan_kernel(
    const unsigned short* __restrict__ convo, const float* __restrict__ dtv,
    const float* __restrict__ dAv, unsigned short* __restrict__ y)
{
  __shared__ float BC[8][256];   // per step: [0,128)=B, [128,256)=C
  __shared__ float X[8][8];
  __shared__ float DT[8];
  __shared__ float DA[8];
  const int t = threadIdx.x;
  const int pq = blockIdx.x & 7;
  const int h = (blockIdx.x >> 3) & 31;
  const int b = blockIdx.x >> 8;
  const int pl = t >> 4;         // 0..7 local p
  const int ng = t & 15;         // 16-lane n-group
  const int n0 = ng * 8;
  float st[8];
  #pragma unroll
  for (int j = 0; j < 8; j++) st[j] = 0.0f;
  const size_t rowbase = (size_t)b * 4096;

  for (int l0 = 0; l0 < 4096; l0 += 8) {
    if (t < 8) {
      bf8_to_f32(convo + (rowbase + l0 + t) * 2304 + h*64 + pq*8, &X[t][0]);
    } else if (t < 16) {
      DT[t - 8]  = dtv[(rowbase + l0 + (t - 8)) * 32 + h];
    } else if (t < 24) {
      DA[t - 16] = dAv[(rowbase + l0 + (t - 16)) * 32 + h];
    }
    {
      int c = t, s = c >> 5, j = c & 31;
      bf8_to_f32(convo + (rowbase + l0 + s) * 2304 + 2048 + j*8, &BC[s][j*8]);
      c = t + 128; s = c >> 5; j = c & 31;
      bf8_to_f32(convo + (rowbase + l0 + s) * 2304 + 2048 + j*8, &BC[s][j*8]);
    }
    __syncthreads();
    #pragma unroll
    for (int s = 0; s < 8; s++) {
      float dA = DA[s];
      float u  = DT[s] * X[s][pl];
      float4 B0 = *(const float4*)&BC[s][n0];
      float4 B1 = *(const float4*)&BC[s][n0 + 4];
      float4 C0 = *(const float4*)&BC[s][128 + n0];
      float4 C1 = *(const float4*)&BC[s][128 + n0 + 4];
      float acc;
      st[0] = fmaf(st[0], dA, u*B0.x); acc = st[0]*C0.x;
      st[1] = fmaf(st[1], dA, u*B0.y); acc = fmaf(st[1], C0.y, acc);
      st[2] = fmaf(st[2], dA, u*B0.z); acc = fmaf(st[2], C0.z, acc);
      st[3] = fmaf(st[3], dA, u*B0.w); acc = fmaf(st[3], C0.w, acc);
      st[4] = fmaf(st[4], dA, u*B1.x); acc = fmaf(st[4], C1.x, acc);
      st[5] = fmaf(st[5], dA, u*B1.y); acc = fmaf(st[5], C1.y, acc);
      st[6] = fmaf(st[6], dA, u*B1.z); acc = fmaf(st[6], C1.z, acc);
      st[7] = fmaf(st[7], dA, u*B1.w); acc = fmaf(st[7], C1.w, acc);
      acc += __shfl_down(acc, 8, 16);
      acc += __shfl_down(acc, 4, 16);
      acc += __shfl_down(acc, 2, 16);
      acc += __shfl_down(acc, 1, 16);
      if (ng == 0)
        y[(rowbase + l0 + s) * 2048 + h*64 + pq*8 + pl] = f2bf(acc);
    }
    __syncthreads();
  }
}

// ---------------- gating: y = (y + D[h]*xh) * silu(z), in place ----------------
__global__ __launch_bounds__(256) void gate_kernel(
    unsigned short* __restrict__ y, const unsigned short* __restrict__ convo,
    const unsigned short* __restrict__ zx, const float* __restrict__ D_param)
{
  size_t i4 = ((size_t)blockIdx.x * 256 + threadIdx.x) * 4;
  if (i4 >= (size_t)8192 * 2048) return;
  int col = (int)(i4 % 2048);
  size_t row = i4 / 2048;
  float D = D_param[col >> 6];
  ushort4 yv = *(ushort4*)(y + i4);
  ushort4 xv = *(const ushort4*)(convo + row * 2304 + col);
  ushort4 zv = *(const ushort4*)(zx + row * 4480 + col);
  float z, s, o[4];
  z = bf2f(zv.x); s = z / (1.0f + expf(-z)); o[0] = (bf2f(yv.x) + D*bf2f(xv.x)) * s;
  z = bf2f(zv.y); s = z / (1.0f + expf(-z)); o[1] = (bf2f(yv.y) + D*bf2f(xv.y)) * s;
  z = bf2f(zv.z); s = z / (1.0f + expf(-z)); o[2] = (bf2f(yv.z) + D*bf2f(xv.z)) * s;
  z = bf2f(zv.w); s = z / (1.0f + expf(-z)); o[3] = (bf2f(yv.w) + D*bf2f(xv.w)) * s;
  *(ushort4*)(y + i4) = make_ushort4(f2bf(o[0]), f2bf(o[1]), f2bf(o[2]), f2bf(o[3]));
}

// ---------------- SwiGLU activation: g = silu(g) * u, in place ----------------
__global__ __launch_bounds__(256) void act_kernel(
    unsigned short* __restrict__ g, const unsigned short* __restrict__ u)
{
  size_t i4 = ((size_t)blockIdx.x * 256 + threadIdx.x) * 4;
  if (i4 >= (size_t)8192 * 4096) return;
  ushort4 gv = *(ushort4*)(g + i4);
  ushort4 uv = *(const ushort4*)(u + i4);
  float x, s, o[4];
  x = bf2f(gv.x); s = x / (1.0f + expf(-x)); o[0] = s * bf2f(uv.x);
  x = bf2f(gv.y); s = x / (1.0f + expf(-x)); o[1] = s * bf2f(uv.y);
  x = bf2f(gv.z); s = x / (1.0f + expf(-x)); o[2] = s * bf2f(uv.z);
  x = bf2f(gv.w); s = x / (1.0f + expf(-x)); o[3] = s * bf2f(uv.w);
  *(ushort4*)(g + i4) = make_ushort4(f2bf(o[0]), f2bf(o[1]), f2bf(o[2]), f2bf(o[3]));
}

// ---------------- workspace arena (bytes) ----------------
static constexpr size_t OFF_RES1 = 0;            // fp32 8192x1024
static constexpr size_t OFF_H1   = 33554432;     // bf16 8192x1024   (h1, then mamba_out)
static constexpr size_t OFF_Y    = 50331648;     // bf16 8192x2048   (y, then gated)
static constexpr size_t OFF_W    = 83886080;     // bf16 weight staging (<= 4480x1024)
static constexpr size_t OFF_ZX   = 93061120;     // bf16 8192x4480   (zxbcdt, then g_out)
static constexpr size_t OFF_CONV = 166461440;    // bf16 8192x2304   (conv_out, then h2)
static constexpr size_t OFF_DT   = 204210176;    // fp32 8192x32
static constexpr size_t OFF_DA   = 205258752;    // fp32 8192x32
static constexpr size_t OFF_U    = 0;            // bf16 8192x4096   (overlaps dead res1/h1/y)

extern "C" void kernel_launch(void* const* d_in, const int* in_sizes, int n_in,
                              void* d_out, int out_size, void* d_ws, size_t ws_size,
                              hipStream_t stream) {
  const float* hid      = (const float*)d_in[0];
  const float* resid    = (const float*)d_in[1];
  const float* ssm_w    = (const float*)d_in[2];
  const float* mlp_w    = (const float*)d_in[3];
  const float* in_proj  = (const float*)d_in[4];
  const float* conv_w   = (const float*)d_in[5];
  const float* conv_b   = (const float*)d_in[6];
  const float* dt_bias  = (const float*)d_in[7];
  const float* A_log    = (const float*)d_in[8];
  const float* D_param  = (const float*)d_in[9];
  const float* out_proj = (const float*)d_in[10];
  const float* gate_w   = (const float*)d_in[11];
  const float* up_w     = (const float*)d_in[12];
  const float* down_w   = (const float*)d_in[13];
  float* out = (float*)d_out;                       // fp32 output: [h | res]
  char* ws = (char*)d_ws;

  float*          res1  = (float*)(ws + OFF_RES1);
  unsigned short* h1    = (unsigned short*)(ws + OFF_H1);
  unsigned short* yb    = (unsigned short*)(ws + OFF_Y);
  unsigned short* Wb    = (unsigned short*)(ws + OFF_W);
  unsigned short* zx    = (unsigned short*)(ws + OFF_ZX);
  unsigned short* convo = (unsigned short*)(ws + OFF_CONV);
  float*          dtv   = (float*)(ws + OFF_DT);
  float*          dAv   = (float*)(ws + OFF_DA);
  unsigned short* ub    = (unsigned short*)(ws + OFF_U);

  rmsnorm1_kernel<<<8192, 256, 0, stream>>>(hid, resid, ssm_w, res1, h1);
  cast_w<<<4480, 256, 0, stream>>>(in_proj, Wb, 4384, 1024, 4480);
  gemm_bt<unsigned short><<<dim3(35, 64), 256, 0, stream>>>(h1, Wb, zx, 8192, 4480, 1024, 4480);
  conv_dt_kernel<<<74752, 256, 0, stream>>>(zx, conv_w, conv_b, dt_bias, A_log,
                                            convo, dtv, dAv);
  scan_kernel<<<512, 128, 0, stream>>>(convo, dtv, dAv, yb);
  gate_kernel<<<16384, 256, 0, stream>>>(yb, convo, zx, D_param);
  cast_w<<<2048, 256, 0, stream>>>(out_proj, Wb, 1024, 2048, 1024);
  gemm_bt<unsigned short><<<dim3(8, 64), 256, 0, stream>>>(yb, Wb, h1, 8192, 1024, 2048, 1024);
  // res (output 1, fp32) -> out + 8388608
  rmsnorm2_kernel<<<8192, 256, 0, stream>>>(h1, res1, mlp_w, out + 8388608, convo);
  cast_w<<<4096, 256, 0, stream>>>(gate_w, Wb, 4096, 1024, 4096);
  gemm_bt<unsigned short><<<dim3(32, 64), 256, 0, stream>>>(convo, Wb, zx, 8192, 4096, 1024, 4096);
  cast_w<<<4096, 256, 0, stream>>>(up_w, Wb, 4096, 1024, 4096);
  gemm_bt<unsigned short><<<dim3(32, 64), 256, 0, stream>>>(convo, Wb, ub, 8192, 4096, 1024, 4096);
  act_kernel<<<32768, 256, 0, stream>>>(zx, ub);
  cast_w<<<4096, 256, 0, stream>>>(down_w, Wb, 1024, 4096, 1024);
  // h (output 0, fp32) -> out[0..8388608)
  gemm_bt<float><<<dim3(8, 64), 256, 0, stream>>>(zx, Wb, out, 8192, 1024, 4096, 1024);
}

// Round 4
// 2130.596 us; speedup vs baseline: 1.0938x; 1.0938x over previous
//
#include <hip/hip_runtime.h>

typedef __bf16 bf16x8 __attribute__((ext_vector_type(8)));
typedef float  f32x4  __attribute__((ext_vector_type(4)));

#define GLOAD_LDS16(gp, lp) \
  __builtin_amdgcn_global_load_lds((const __attribute__((address_space(1))) void*)(gp), \
                                   (__attribute__((address_space(3))) void*)(lp), 16, 0, 0)

#define LDS_SYNC() asm volatile("s_waitcnt lgkmcnt(0)" ::: "memory")

__device__ __forceinline__ unsigned short f2bf(float f) {
  unsigned u = __float_as_uint(f);
  u += 0x7fffu + ((u >> 16) & 1u);
  return (unsigned short)(u >> 16);
}
__device__ __forceinline__ float bf2f(unsigned short h) {
  return __uint_as_float(((unsigned)h) << 16);
}
__device__ __forceinline__ f32x4 splat4(float v) { f32x4 r = {v, v, v, v}; return r; }
__device__ __forceinline__ int physq(int q) { return q ^ ((q >> 3) & 1); }

__device__ __forceinline__ void store_out(unsigned short* C, size_t idx, float v) {
  C[idx] = f2bf(v);
}
__device__ __forceinline__ void store_out(float* C, size_t idx, float v) {
  C[idx] = v;
}

// ---------------- RMSNorm (prenorm) #1: fp32 hidden + fp32 residual ----------------
__global__ __launch_bounds__(256) void rmsnorm1_kernel(
    const float* __restrict__ hid, const float* __restrict__ resin,
    const float* __restrict__ w, float* __restrict__ resout,
    unsigned short* __restrict__ hout)
{
  const int row = blockIdx.x, t = threadIdx.x;
  const size_t base = (size_t)row * 1024;
  float4 h = ((const float4*)(hid + base))[t];
  float4 r = ((const float4*)(resin + base))[t];
  float4 s; s.x = h.x + r.x; s.y = h.y + r.y; s.z = h.z + r.z; s.w = h.w + r.w;
  float ss = s.x*s.x + s.y*s.y + s.z*s.z + s.w*s.w;
  #pragma unroll
  for (int off = 32; off; off >>= 1) ss += __shfl_down(ss, off, 64);
  __shared__ float red[4];
  if ((t & 63) == 0) red[t >> 6] = ss;
  __syncthreads();
  float tot = red[0] + red[1] + red[2] + red[3];
  float sc = rsqrtf(tot * (1.0f/1024.0f) + 1e-5f);
  ((float4*)(resout + base))[t] = s;
  float4 wv = ((const float4*)w)[t];
  ushort4 o = make_ushort4(f2bf(s.x*sc*wv.x), f2bf(s.y*sc*wv.y),
                           f2bf(s.z*sc*wv.z), f2bf(s.w*sc*wv.w));
  ((ushort4*)(hout + base))[t] = o;
}

// ---------------- RMSNorm (prenorm) #2: bf16 mamba_out + fp32 res1 ----------------
__global__ __launch_bounds__(256) void rmsnorm2_kernel(
    const unsigned short* __restrict__ mo, const float* __restrict__ res1,
    const float* __restrict__ w, float* __restrict__ res_out,
    unsigned short* __restrict__ h2)
{
  const int row = blockIdx.x, t = threadIdx.x;
  const size_t base = (size_t)row * 1024;
  float4 r = ((const float4*)(res1 + base))[t];
  ushort4 m = ((const ushort4*)(mo + base))[t];
  float4 s; s.x = r.x + bf2f(m.x); s.y = r.y + bf2f(m.y);
            s.z = r.z + bf2f(m.z); s.w = r.w + bf2f(m.w);
  float ss = s.x*s.x + s.y*s.y + s.z*s.z + s.w*s.w;
  #pragma unroll
  for (int off = 32; off; off >>= 1) ss += __shfl_down(ss, off, 64);
  __shared__ float red[4];
  if ((t & 63) == 0) red[t >> 6] = ss;
  __syncthreads();
  float tot = red[0] + red[1] + red[2] + red[3];
  float sc = rsqrtf(tot * (1.0f/1024.0f) + 1e-5f);
  ((float4*)(res_out + base))[t] = s;
  float4 wv = ((const float4*)w)[t];
  ((ushort4*)(h2 + base))[t] = make_ushort4(f2bf(s.x*sc*wv.x), f2bf(s.y*sc*wv.y),
                                            f2bf(s.z*sc*wv.z), f2bf(s.w*sc*wv.w));
}

// ---------------- fp32 -> bf16 weight cast with row padding ----------------
__global__ __launch_bounds__(256) void cast_w(
    const float* __restrict__ src, unsigned short* __restrict__ dst,
    int rows, int cols, int prows)
{
  size_t i4 = ((size_t)blockIdx.x * 256 + threadIdx.x) * 4;
  size_t total = (size_t)prows * cols;
  if (i4 >= total) return;
  int r = (int)(i4 / cols);
  ushort4 o;
  if (r < rows) {
    float4 v = *(const float4*)(src + i4);
    o = make_ushort4(f2bf(v.x), f2bf(v.y), f2bf(v.z), f2bf(v.w));
  } else {
    o = make_ushort4(0, 0, 0, 0);
  }
  *(ushort4*)(dst + i4) = o;
}

// ---------------- bf16 GEMM:  C[m,n] = sum_k A[m,k] * W[n,k]  (NT) ----------------
template <typename OutT>
__global__ __launch_bounds__(256) void gemm_bt(
    const unsigned short* __restrict__ A, const unsigned short* __restrict__ W,
    OutT* __restrict__ C, int M, int N, int K, int ldc)
{
  __shared__ unsigned short As[128 * 32];
  __shared__ unsigned short Bs[128 * 32];
  const int tid = threadIdx.x;
  const int wave = tid >> 6, lane = tid & 63;
  const int m0 = blockIdx.y << 7, n0 = blockIdx.x << 7;
  const int lr = lane >> 2;
  const int lk = (lane & 3) << 3;
  const int wm = (wave >> 1) << 6, wn = (wave & 1) << 6;
  const int fr = lane & 15, fq = lane >> 4;

  f32x4 acc[4][4];
  #pragma unroll
  for (int i = 0; i < 4; i++)
    #pragma unroll
    for (int j = 0; j < 4; j++)
      #pragma unroll
      for (int r = 0; r < 4; r++) acc[i][j][r] = 0.0f;

  const unsigned short* Abase = A + (size_t)(m0 + wave*32 + lr) * K + lk;
  const unsigned short* Wbase = W + (size_t)(n0 + wave*32 + lr) * K + lk;
  const size_t rstep = (size_t)16 * K;
  unsigned short* AsW = As + (wave*32) * 32;
  unsigned short* BsW = Bs + (wave*32) * 32;

  for (int k0 = 0; k0 < K; k0 += 32) {
    GLOAD_LDS16(Abase + k0,         AsW);
    GLOAD_LDS16(Abase + k0 + rstep, AsW + 16*32);
    GLOAD_LDS16(Wbase + k0,         BsW);
    GLOAD_LDS16(Wbase + k0 + rstep, BsW + 16*32);
    __syncthreads();
    bf16x8 af[4], bfv[4];
    #pragma unroll
    for (int i = 0; i < 4; i++) {
      af[i]  = *(const bf16x8*)(As + (wm + i*16 + fr) * 32 + fq*8);
      bfv[i] = *(const bf16x8*)(Bs + (wn + i*16 + fr) * 32 + fq*8);
    }
    #pragma unroll
    for (int i = 0; i < 4; i++)
      #pragma unroll
      for (int j = 0; j < 4; j++)
        acc[i][j] = __builtin_amdgcn_mfma_f32_16x16x32_bf16(af[i], bfv[j], acc[i][j], 0, 0, 0);
    __syncthreads();
  }

  #pragma unroll
  for (int i = 0; i < 4; i++)
    #pragma unroll
    for (int j = 0; j < 4; j++)
      #pragma unroll
      for (int r = 0; r < 4; r++) {
        int gm = m0 + wm + i*16 + fq*4 + r;
        int gn = n0 + wn + j*16 + fr;
        store_out(C, (size_t)gm * ldc + gn, acc[i][j][r]);
      }
}

// ---------------- causal depthwise conv (K=4) + silu, and dt/dA precompute ----------------
__global__ __launch_bounds__(256) void conv_dt_kernel(
    const unsigned short* __restrict__ zx, const float* __restrict__ conv_w,
    const float* __restrict__ conv_b, const float* __restrict__ dt_bias,
    const float* __restrict__ A_log, unsigned short* __restrict__ conv_out,
    float2* __restrict__ dtda)
{
  size_t idx = (size_t)blockIdx.x * 256 + threadIdx.x;
  if (idx >= (size_t)8192 * 2336) return;
  int c = (int)(idx % 2336);
  int row = (int)(idx / 2336);
  int l = row & 4095;
  if (c < 2304) {
    float acc = conv_b[c];
    const float* wp = conv_w + c * 4;
    #pragma unroll
    for (int j = 0; j < 4; j++) {
      int ls = l - 3 + j;
      if (ls >= 0) acc += bf2f(zx[(size_t)(row - 3 + j) * 4480 + 2048 + c]) * wp[j];
    }
    float s = acc / (1.0f + expf(-acc));
    conv_out[(size_t)row * 2304 + c] = f2bf(s);
  } else {
    int h = c - 2304;
    float draw = bf2f(zx[(size_t)row * 4480 + 4352 + h]) + dt_bias[h];
    float sp = (draw > 20.0f) ? draw : log1pf(expf(draw));
    float Ah = -expf(A_log[h]);
    dtda[(size_t)row * 32 + h] = make_float2(sp, expf(sp * Ah));
  }
}

// ---------------- selective scan: 1 wave per (b,h,p-octant), dbuf pipeline --------
// Lane: ng = t&15 (8 n each), pl = t>>4 (2 p each). st = f32x4[4] = 16 fp32 state.
// Block of 8 steps: global->reg prefetch (issued 1 block ahead), f32 LDS with
// XOR quad swizzle (2-way conflicts only), wave-synchronous (no s_barrier).
__global__ __launch_bounds__(64) void scan_kernel(
    const unsigned short* __restrict__ convo, const float2* __restrict__ dtda,
    unsigned short* __restrict__ y)
{
  __shared__ float  BCs[2][8][256];   // per step: B f32[128], C f32[128], swizzled quads
  __shared__ uint4  Xs[2][8];         // per step: 8 bf16 x-values (octant)
  __shared__ float2 DTs[2][8];        // per step: (dt, dA)
  const int t  = threadIdx.x;
  const int pq = blockIdx.x & 7;
  const int h  = (blockIdx.x >> 3) & 31;
  const int b  = blockIdx.x >> 8;
  const int ng = t & 15, pl = t >> 4;
  const size_t rowbase = (size_t)b * 4096;
  const int oB0 = physq(2*ng) * 4,      oB1 = physq(2*ng + 1) * 4;
  const int oC0 = physq(32 + 2*ng) * 4, oC1 = physq(33 + 2*ng) * 4;
  const int sq  = physq(t) * 4;        // staging write offset (floats)
  const int xs  = t & 7;               // step this lane stages for X / DT

  f32x4 st0 = splat4(0.0f), st1 = splat4(0.0f);  // p0 = pq*8+pl*2
  f32x4 st2 = splat4(0.0f), st3 = splat4(0.0f);  // p1 = p0+1

  uint2  bcr[8];
  uint4  xr = {0, 0, 0, 0};
  float2 ddr = make_float2(0.0f, 0.0f);

  auto ldregs = [&](int blk) {
    const size_t r0 = rowbase + (size_t)blk * 8;
    const unsigned short* src = convo + r0 * 2304 + 2048 + t * 4;
    #pragma unroll
    for (int s = 0; s < 8; s++)
      bcr[s] = *(const uint2*)(src + (size_t)s * 2304);
    if (t < 8) {
      xr = *(const uint4*)(convo + (r0 + xs) * 2304 + h * 64 + pq * 8);
    } else if (t < 16) {
      ddr = dtda[(r0 + xs) * 32 + h];
    }
  };

  auto stage = [&](int nb) {
    #pragma unroll
    for (int s = 0; s < 8; s++) {
      f32x4 v;
      v[0] = __uint_as_float(bcr[s].x << 16);
      v[1] = __uint_as_float(bcr[s].x & 0xffff0000u);
      v[2] = __uint_as_float(bcr[s].y << 16);
      v[3] = __uint_as_float(bcr[s].y & 0xffff0000u);
      *(f32x4*)(&BCs[nb][s][sq]) = v;
    }
    if (t < 8) Xs[nb][xs] = xr;
    else if (t < 16) DTs[nb][xs] = ddr;
  };

  auto compute = [&](int cur, int blk) {
    #pragma unroll
    for (int s = 0; s < 8; s++) {
      const float* bc = &BCs[cur][s][0];
      f32x4 B0 = *(const f32x4*)(bc + oB0);
      f32x4 B1 = *(const f32x4*)(bc + oB1);
      f32x4 C0 = *(const f32x4*)(bc + oC0);
      f32x4 C1 = *(const f32x4*)(bc + oC1);
      float2 dd = DTs[cur][s];
      unsigned xw = ((const unsigned*)&Xs[cur][s])[pl];
      float x0 = __uint_as_float(xw << 16);
      float x1 = __uint_as_float(xw & 0xffff0000u);
      f32x4 Bp0 = B0 * splat4(dd.x);
      f32x4 Bp1 = B1 * splat4(dd.x);
      f32x4 dA = splat4(dd.y);
      st0 = st0 * dA + Bp0 * splat4(x0);
      st1 = st1 * dA + Bp1 * splat4(x0);
      st2 = st2 * dA + Bp0 * splat4(x1);
      st3 = st3 * dA + Bp1 * splat4(x1);
      f32x4 a0v = st0 * C0 + st1 * C1;
      f32x4 a1v = st2 * C0 + st3 * C1;
      float a0 = (a0v[0] + a0v[2]) + (a0v[1] + a0v[3]);
      float a1 = (a1v[0] + a1v[2]) + (a1v[1] + a1v[3]);
      #pragma unroll
      for (int d = 1; d < 16; d <<= 1) {
        a0 += __shfl_xor(a0, d);
        a1 += __shfl_xor(a1, d);
      }
      if (ng == 0) {
        unsigned pack = (unsigned)f2bf(a0) | ((unsigned)f2bf(a1) << 16);
        ((unsigned*)y)[(rowbase + (size_t)blk * 8 + s) * 1024 + h * 32 + pq * 4 + pl] = pack;
      }
    }
  };

  ldregs(0);
  stage(0);
  LDS_SYNC();
  for (int blk = 0; blk < 512; blk += 2) {
    ldregs(blk + 1);
    compute(0, blk);
    stage(1);
    LDS_SYNC();
    if (blk + 2 < 512) ldregs(blk + 2);
    compute(1, blk + 1);
    if (blk + 2 < 512) stage(0);
    LDS_SYNC();
  }
}

// ---------------- gating: y = (y + D[h]*xh) * silu(z), in place ----------------
__global__ __launch_bounds__(256) void gate_kernel(
    unsigned short* __restrict__ y, const unsigned short* __restrict__ convo,
    const unsigned short* __restrict__ zx, const float* __restrict__ D_param)
{
  size_t i4 = ((size_t)blockIdx.x * 256 + threadIdx.x) * 4;
  if (i4 >= (size_t)8192 * 2048) return;
  int col = (int)(i4 % 2048);
  size_t row = i4 / 2048;
  float D = D_param[col >> 6];
  ushort4 yv = *(ushort4*)(y + i4);
  ushort4 xv = *(const ushort4*)(convo + row * 2304 + col);
  ushort4 zv = *(const ushort4*)(zx + row * 4480 + col);
  float z, s, o[4];
  z = bf2f(zv.x); s = z / (1.0f + expf(-z)); o[0] = (bf2f(yv.x) + D*bf2f(xv.x)) * s;
  z = bf2f(zv.y); s = z / (1.0f + expf(-z)); o[1] = (bf2f(yv.y) + D*bf2f(xv.y)) * s;
  z = bf2f(zv.z); s = z / (1.0f + expf(-z)); o[2] = (bf2f(yv.z) + D*bf2f(xv.z)) * s;
  z = bf2f(zv.w); s = z / (1.0f + expf(-z)); o[3] = (bf2f(yv.w) + D*bf2f(xv.w)) * s;
  *(ushort4*)(y + i4) = make_ushort4(f2bf(o[0]), f2bf(o[1]), f2bf(o[2]), f2bf(o[3]));
}

// ---------------- SwiGLU activation: g = silu(g) * u, in place ----------------
__global__ __launch_bounds__(256) void act_kernel(
    unsigned short* __restrict__ g, const unsigned short* __restrict__ u)
{
  size_t i4 = ((size_t)blockIdx.x * 256 + threadIdx.x) * 4;
  if (i4 >= (size_t)8192 * 4096) return;
  ushort4 gv = *(ushort4*)(g + i4);
  ushort4 uv = *(const ushort4*)(u + i4);
  float x, s, o[4];
  x = bf2f(gv.x); s = x / (1.0f + expf(-x)); o[0] = s * bf2f(uv.x);
  x = bf2f(gv.y); s = x / (1.0f + expf(-x)); o[1] = s * bf2f(uv.y);
  x = bf2f(gv.z); s = x / (1.0f + expf(-x)); o[2] = s * bf2f(uv.z);
  x = bf2f(gv.w); s = x / (1.0f + expf(-x)); o[3] = s * bf2f(uv.w);
  *(ushort4*)(g + i4) = make_ushort4(f2bf(o[0]), f2bf(o[1]), f2bf(o[2]), f2bf(o[3]));
}

// ---------------- workspace arena (bytes) ----------------
static constexpr size_t OFF_RES1 = 0;            // fp32 8192x1024
static constexpr size_t OFF_H1   = 33554432;     // bf16 8192x1024   (h1, then mamba_out)
static constexpr size_t OFF_Y    = 50331648;     // bf16 8192x2048   (y, then gated)
static constexpr size_t OFF_W    = 83886080;     // bf16 weight staging (<= 4480x1024)
static constexpr size_t OFF_ZX   = 93061120;     // bf16 8192x4480   (zxbcdt, then g_out)
static constexpr size_t OFF_CONV = 166461440;    // bf16 8192x2304   (conv_out, then h2)
static constexpr size_t OFF_DTDA = 204210176;    // float2 8192x32 (dt, dA) = 2 MB
static constexpr size_t OFF_U    = 0;            // bf16 8192x4096   (overlaps dead res1/h1/y)

extern "C" void kernel_launch(void* const* d_in, const int* in_sizes, int n_in,
                              void* d_out, int out_size, void* d_ws, size_t ws_size,
                              hipStream_t stream) {
  const float* hid      = (const float*)d_in[0];
  const float* resid    = (const float*)d_in[1];
  const float* ssm_w    = (const float*)d_in[2];
  const float* mlp_w    = (const float*)d_in[3];
  const float* in_proj  = (const float*)d_in[4];
  const float* conv_w   = (const float*)d_in[5];
  const float* conv_b   = (const float*)d_in[6];
  const float* dt_bias  = (const float*)d_in[7];
  const float* A_log    = (const float*)d_in[8];
  const float* D_param  = (const float*)d_in[9];
  const float* out_proj = (const float*)d_in[10];
  const float* gate_w   = (const float*)d_in[11];
  const float* up_w     = (const float*)d_in[12];
  const float* down_w   = (const float*)d_in[13];
  float* out = (float*)d_out;                       // fp32 output: [h | res]
  char* ws = (char*)d_ws;

  float*          res1  = (float*)(ws + OFF_RES1);
  unsigned short* h1    = (unsigned short*)(ws + OFF_H1);
  unsigned short* yb    = (unsigned short*)(ws + OFF_Y);
  unsigned short* Wb    = (unsigned short*)(ws + OFF_W);
  unsigned short* zx    = (unsigned short*)(ws + OFF_ZX);
  unsigned short* convo = (unsigned short*)(ws + OFF_CONV);
  float2*         dtda  = (float2*)(ws + OFF_DTDA);
  unsigned short* ub    = (unsigned short*)(ws + OFF_U);

  rmsnorm1_kernel<<<8192, 256, 0, stream>>>(hid, resid, ssm_w, res1, h1);
  cast_w<<<4480, 256, 0, stream>>>(in_proj, Wb, 4384, 1024, 4480);
  gemm_bt<unsigned short><<<dim3(35, 64), 256, 0, stream>>>(h1, Wb, zx, 8192, 4480, 1024, 4480);
  conv_dt_kernel<<<74752, 256, 0, stream>>>(zx, conv_w, conv_b, dt_bias, A_log,
                                            convo, dtda);
  scan_kernel<<<512, 64, 0, stream>>>(convo, dtda, yb);
  gate_kernel<<<16384, 256, 0, stream>>>(yb, convo, zx, D_param);
  cast_w<<<2048, 256, 0, stream>>>(out_proj, Wb, 1024, 2048, 1024);
  gemm_bt<unsigned short><<<dim3(8, 64), 256, 0, stream>>>(yb, Wb, h1, 8192, 1024, 2048, 1024);
  rmsnorm2_kernel<<<8192, 256, 0, stream>>>(h1, res1, mlp_w, out + 8388608, convo);
  cast_w<<<4096, 256, 0, stream>>>(gate_w, Wb, 4096, 1024, 4096);
  gemm_bt<unsigned short><<<dim3(32, 64), 256, 0, stream>>>(convo, Wb, zx, 8192, 4096, 1024, 4096);
  cast_w<<<4096, 256, 0, stream>>>(up_w, Wb, 4096, 1024, 4096);
  gemm_bt<unsigned short><<<dim3(32, 64), 256, 0, stream>>>(convo, Wb, ub, 8192, 4096, 1024, 4096);
  act_kernel<<<32768, 256, 0, stream>>>(zx, ub);
  cast_w<<<4096, 256, 0, stream>>>(down_w, Wb, 1024, 4096, 1024);
  gemm_bt<float><<<dim3(8, 64), 256, 0, stream>>>(zx, Wb, out, 8192, 1024, 4096, 1024);
}

// Round 5
// 1714.917 us; speedup vs baseline: 1.3589x; 1.2424x over previous
//
#include <hip/hip_runtime.h>

typedef __bf16 bf16x8 __attribute__((ext_vector_type(8)));
typedef float  f32x4  __attribute__((ext_vector_type(4)));

#define GLOAD_LDS16(gp, lp) \
  __builtin_amdgcn_global_load_lds((const __attribute__((address_space(1))) void*)(gp), \
                                   (__attribute__((address_space(3))) void*)(lp), 16, 0, 0)

#define LDS_SYNC() asm volatile("s_waitcnt lgkmcnt(0)" ::: "memory")

__device__ __forceinline__ unsigned short f2bf(float f) {
  unsigned u = __float_as_uint(f);
  u += 0x7fffu + ((u >> 16) & 1u);
  return (unsigned short)(u >> 16);
}
__device__ __forceinline__ float bf2f(unsigned short h) {
  return __uint_as_float(((unsigned)h) << 16);
}
__device__ __forceinline__ f32x4 splat4(float v) { f32x4 r = {v, v, v, v}; return r; }
__device__ __forceinline__ int physq(int q) { return q ^ ((q >> 3) & 1); }

// 16-lane (DPP row) sum reduction, result valid in lane 15 of each row.
// row_shr:N = 0x110+N; bound_ctrl=true zero-fills shifted-in lanes.
template <int CTRL>
__device__ __forceinline__ float dpp_add(float v) {
  int t = __builtin_amdgcn_update_dpp(0, __float_as_int(v), CTRL, 0xF, 0xF, true);
  return v + __int_as_float(t);
}
__device__ __forceinline__ float row_sum16(float v) {
  v = dpp_add<0x111>(v);  // row_shr:1
  v = dpp_add<0x112>(v);  // row_shr:2
  v = dpp_add<0x114>(v);  // row_shr:4
  v = dpp_add<0x118>(v);  // row_shr:8
  return v;               // lane 15 of each 16-row holds the sum
}

__device__ __forceinline__ void store_out(unsigned short* C, size_t idx, float v) {
  C[idx] = f2bf(v);
}
__device__ __forceinline__ void store_out(float* C, size_t idx, float v) {
  C[idx] = v;
}

// ---------------- RMSNorm (prenorm) #1: fp32 hidden + fp32 residual ----------------
__global__ __launch_bounds__(256) void rmsnorm1_kernel(
    const float* __restrict__ hid, const float* __restrict__ resin,
    const float* __restrict__ w, float* __restrict__ resout,
    unsigned short* __restrict__ hout)
{
  const int row = blockIdx.x, t = threadIdx.x;
  const size_t base = (size_t)row * 1024;
  float4 h = ((const float4*)(hid + base))[t];
  float4 r = ((const float4*)(resin + base))[t];
  float4 s; s.x = h.x + r.x; s.y = h.y + r.y; s.z = h.z + r.z; s.w = h.w + r.w;
  float ss = s.x*s.x + s.y*s.y + s.z*s.z + s.w*s.w;
  #pragma unroll
  for (int off = 32; off; off >>= 1) ss += __shfl_down(ss, off, 64);
  __shared__ float red[4];
  if ((t & 63) == 0) red[t >> 6] = ss;
  __syncthreads();
  float tot = red[0] + red[1] + red[2] + red[3];
  float sc = rsqrtf(tot * (1.0f/1024.0f) + 1e-5f);
  ((float4*)(resout + base))[t] = s;
  float4 wv = ((const float4*)w)[t];
  ushort4 o = make_ushort4(f2bf(s.x*sc*wv.x), f2bf(s.y*sc*wv.y),
                           f2bf(s.z*sc*wv.z), f2bf(s.w*sc*wv.w));
  ((ushort4*)(hout + base))[t] = o;
}

// ---------------- RMSNorm (prenorm) #2: bf16 mamba_out + fp32 res1 ----------------
__global__ __launch_bounds__(256) void rmsnorm2_kernel(
    const unsigned short* __restrict__ mo, const float* __restrict__ res1,
    const float* __restrict__ w, float* __restrict__ res_out,
    unsigned short* __restrict__ h2)
{
  const int row = blockIdx.x, t = threadIdx.x;
  const size_t base = (size_t)row * 1024;
  float4 r = ((const float4*)(res1 + base))[t];
  ushort4 m = ((const ushort4*)(mo + base))[t];
  float4 s; s.x = r.x + bf2f(m.x); s.y = r.y + bf2f(m.y);
            s.z = r.z + bf2f(m.z); s.w = r.w + bf2f(m.w);
  float ss = s.x*s.x + s.y*s.y + s.z*s.z + s.w*s.w;
  #pragma unroll
  for (int off = 32; off; off >>= 1) ss += __shfl_down(ss, off, 64);
  __shared__ float red[4];
  if ((t & 63) == 0) red[t >> 6] = ss;
  __syncthreads();
  float tot = red[0] + red[1] + red[2] + red[3];
  float sc = rsqrtf(tot * (1.0f/1024.0f) + 1e-5f);
  ((float4*)(res_out + base))[t] = s;
  float4 wv = ((const float4*)w)[t];
  ((ushort4*)(h2 + base))[t] = make_ushort4(f2bf(s.x*sc*wv.x), f2bf(s.y*sc*wv.y),
                                            f2bf(s.z*sc*wv.z), f2bf(s.w*sc*wv.w));
}

// ---------------- fp32 -> bf16 weight cast with row padding ----------------
__global__ __launch_bounds__(256) void cast_w(
    const float* __restrict__ src, unsigned short* __restrict__ dst,
    int rows, int cols, int prows)
{
  size_t i4 = ((size_t)blockIdx.x * 256 + threadIdx.x) * 4;
  size_t total = (size_t)prows * cols;
  if (i4 >= total) return;
  int r = (int)(i4 / cols);
  ushort4 o;
  if (r < rows) {
    float4 v = *(const float4*)(src + i4);
    o = make_ushort4(f2bf(v.x), f2bf(v.y), f2bf(v.z), f2bf(v.w));
  } else {
    o = make_ushort4(0, 0, 0, 0);
  }
  *(ushort4*)(dst + i4) = o;
}

// ---------------- bf16 GEMM:  C[m,n] = sum_k A[m,k] * W[n,k]  (NT) ----------------
template <typename OutT>
__global__ __launch_bounds__(256) void gemm_bt(
    const unsigned short* __restrict__ A, const unsigned short* __restrict__ W,
    OutT* __restrict__ C, int M, int N, int K, int ldc)
{
  __shared__ unsigned short As[128 * 32];
  __shared__ unsigned short Bs[128 * 32];
  const int tid = threadIdx.x;
  const int wave = tid >> 6, lane = tid & 63;
  const int m0 = blockIdx.y << 7, n0 = blockIdx.x << 7;
  const int lr = lane >> 2;
  const int lk = (lane & 3) << 3;
  const int wm = (wave >> 1) << 6, wn = (wave & 1) << 6;
  const int fr = lane & 15, fq = lane >> 4;

  f32x4 acc[4][4];
  #pragma unroll
  for (int i = 0; i < 4; i++)
    #pragma unroll
    for (int j = 0; j < 4; j++)
      #pragma unroll
      for (int r = 0; r < 4; r++) acc[i][j][r] = 0.0f;

  const unsigned short* Abase = A + (size_t)(m0 + wave*32 + lr) * K + lk;
  const unsigned short* Wbase = W + (size_t)(n0 + wave*32 + lr) * K + lk;
  const size_t rstep = (size_t)16 * K;
  unsigned short* AsW = As + (wave*32) * 32;
  unsigned short* BsW = Bs + (wave*32) * 32;

  for (int k0 = 0; k0 < K; k0 += 32) {
    GLOAD_LDS16(Abase + k0,         AsW);
    GLOAD_LDS16(Abase + k0 + rstep, AsW + 16*32);
    GLOAD_LDS16(Wbase + k0,         BsW);
    GLOAD_LDS16(Wbase + k0 + rstep, BsW + 16*32);
    __syncthreads();
    bf16x8 af[4], bfv[4];
    #pragma unroll
    for (int i = 0; i < 4; i++) {
      af[i]  = *(const bf16x8*)(As + (wm + i*16 + fr) * 32 + fq*8);
      bfv[i] = *(const bf16x8*)(Bs + (wn + i*16 + fr) * 32 + fq*8);
    }
    #pragma unroll
    for (int i = 0; i < 4; i++)
      #pragma unroll
      for (int j = 0; j < 4; j++)
        acc[i][j] = __builtin_amdgcn_mfma_f32_16x16x32_bf16(af[i], bfv[j], acc[i][j], 0, 0, 0);
    __syncthreads();
  }

  #pragma unroll
  for (int i = 0; i < 4; i++)
    #pragma unroll
    for (int j = 0; j < 4; j++)
      #pragma unroll
      for (int r = 0; r < 4; r++) {
        int gm = m0 + wm + i*16 + fq*4 + r;
        int gn = n0 + wn + j*16 + fr;
        store_out(C, (size_t)gm * ldc + gn, acc[i][j][r]);
      }
}

// ---------------- causal depthwise conv (K=4) + silu, and dt/dA precompute ----------------
__global__ __launch_bounds__(256) void conv_dt_kernel(
    const unsigned short* __restrict__ zx, const float* __restrict__ conv_w,
    const float* __restrict__ conv_b, const float* __restrict__ dt_bias,
    const float* __restrict__ A_log, unsigned short* __restrict__ conv_out,
    float2* __restrict__ dtda)
{
  size_t idx = (size_t)blockIdx.x * 256 + threadIdx.x;
  if (idx >= (size_t)8192 * 2336) return;
  int c = (int)(idx % 2336);
  int row = (int)(idx / 2336);
  int l = row & 4095;
  if (c < 2304) {
    float acc = conv_b[c];
    const float* wp = conv_w + c * 4;
    #pragma unroll
    for (int j = 0; j < 4; j++) {
      int ls = l - 3 + j;
      if (ls >= 0) acc += bf2f(zx[(size_t)(row - 3 + j) * 4480 + 2048 + c]) * wp[j];
    }
    float s = acc / (1.0f + expf(-acc));
    conv_out[(size_t)row * 2304 + c] = f2bf(s);
  } else {
    int h = c - 2304;
    float draw = bf2f(zx[(size_t)row * 4480 + 4352 + h]) + dt_bias[h];
    float sp = (draw > 20.0f) ? draw : log1pf(expf(draw));
    float Ah = -expf(A_log[h]);
    dtda[(size_t)row * 32 + h] = make_float2(sp, expf(sp * Ah));
  }
}

// ---------------- selective scan: 1 wave per (b,h,p-octant), dbuf pipeline --------
// Lane: ng = t&15 (8 n each), pl = t>>4 (2 p each). st = f32x4[4] = 16 fp32 state.
// Cross-lane y-reduction via DPP row_shr (VALU-only; no ds_bpermute).
__global__ __launch_bounds__(64) void scan_kernel(
    const unsigned short* __restrict__ convo, const float2* __restrict__ dtda,
    unsigned short* __restrict__ y)
{
  __shared__ float  BCs[2][8][256];   // per step: B f32[128], C f32[128], swizzled quads
  __shared__ uint4  Xs[2][8];         // per step: 8 bf16 x-values (octant)
  __shared__ float2 DTs[2][8];        // per step: (dt, dA)
  const int t  = threadIdx.x;
  const int pq = blockIdx.x & 7;
  const int h  = (blockIdx.x >> 3) & 31;
  const int b  = blockIdx.x >> 8;
  const int ng = t & 15, pl = t >> 4;
  const size_t rowbase = (size_t)b * 4096;
  const int oB0 = physq(2*ng) * 4,      oB1 = physq(2*ng + 1) * 4;
  const int oC0 = physq(32 + 2*ng) * 4, oC1 = physq(33 + 2*ng) * 4;
  const int sq  = physq(t) * 4;        // staging write offset (floats)
  const int xs  = t & 7;               // step this lane stages for X / DT

  f32x4 st0 = splat4(0.0f), st1 = splat4(0.0f);  // p0 = pq*8+pl*2
  f32x4 st2 = splat4(0.0f), st3 = splat4(0.0f);  // p1 = p0+1

  uint2  bcr[8];
  uint4  xr = {0, 0, 0, 0};
  float2 ddr = make_float2(0.0f, 0.0f);

  auto ldregs = [&](int blk) {
    const size_t r0 = rowbase + (size_t)blk * 8;
    const unsigned short* src = convo + r0 * 2304 + 2048 + t * 4;
    #pragma unroll
    for (int s = 0; s < 8; s++)
      bcr[s] = *(const uint2*)(src + (size_t)s * 2304);
    if (t < 8) {
      xr = *(const uint4*)(convo + (r0 + xs) * 2304 + h * 64 + pq * 8);
    } else if (t < 16) {
      ddr = dtda[(r0 + xs) * 32 + h];
    }
  };

  auto stage = [&](int nb) {
    #pragma unroll
    for (int s = 0; s < 8; s++) {
      f32x4 v;
      v[0] = __uint_as_float(bcr[s].x << 16);
      v[1] = __uint_as_float(bcr[s].x & 0xffff0000u);
      v[2] = __uint_as_float(bcr[s].y << 16);
      v[3] = __uint_as_float(bcr[s].y & 0xffff0000u);
      *(f32x4*)(&BCs[nb][s][sq]) = v;
    }
    if (t < 8) Xs[nb][xs] = xr;
    else if (t < 16) DTs[nb][xs] = ddr;
  };

  auto compute = [&](int cur, int blk) {
    #pragma unroll
    for (int s = 0; s < 8; s++) {
      const float* bc = &BCs[cur][s][0];
      f32x4 B0 = *(const f32x4*)(bc + oB0);
      f32x4 B1 = *(const f32x4*)(bc + oB1);
      f32x4 C0 = *(const f32x4*)(bc + oC0);
      f32x4 C1 = *(const f32x4*)(bc + oC1);
      float2 dd = DTs[cur][s];
      unsigned xw = ((const unsigned*)&Xs[cur][s])[pl];
      float x0 = __uint_as_float(xw << 16);
      float x1 = __uint_as_float(xw & 0xffff0000u);
      f32x4 Bp0 = B0 * splat4(dd.x);
      f32x4 Bp1 = B1 * splat4(dd.x);
      f32x4 dA = splat4(dd.y);
      st0 = st0 * dA + Bp0 * splat4(x0);
      st1 = st1 * dA + Bp1 * splat4(x0);
      st2 = st2 * dA + Bp0 * splat4(x1);
      st3 = st3 * dA + Bp1 * splat4(x1);
      f32x4 a0v = st0 * C0 + st1 * C1;
      f32x4 a1v = st2 * C0 + st3 * C1;
      float a0 = (a0v[0] + a0v[2]) + (a0v[1] + a0v[3]);
      float a1 = (a1v[0] + a1v[2]) + (a1v[1] + a1v[3]);
      a0 = row_sum16(a0);            // DPP: sum lands in lane 15 of each row
      a1 = row_sum16(a1);
      if (ng == 15) {
        unsigned pack = (unsigned)f2bf(a0) | ((unsigned)f2bf(a1) << 16);
        ((unsigned*)y)[(rowbase + (size_t)blk * 8 + s) * 1024 + h * 32 + pq * 4 + pl] = pack;
      }
    }
  };

  ldregs(0);
  stage(0);
  LDS_SYNC();
  for (int blk = 0; blk < 512; blk += 2) {
    ldregs(blk + 1);
    compute(0, blk);
    stage(1);
    LDS_SYNC();
    if (blk + 2 < 512) ldregs(blk + 2);
    compute(1, blk + 1);
    if (blk + 2 < 512) stage(0);
    LDS_SYNC();
  }
}

// ---------------- gating: y = (y + D[h]*xh) * silu(z), in place ----------------
__global__ __launch_bounds__(256) void gate_kernel(
    unsigned short* __restrict__ y, const unsigned short* __restrict__ convo,
    const unsigned short* __restrict__ zx, const float* __restrict__ D_param)
{
  size_t i4 = ((size_t)blockIdx.x * 256 + threadIdx.x) * 4;
  if (i4 >= (size_t)8192 * 2048) return;
  int col = (int)(i4 % 2048);
  size_t row = i4 / 2048;
  float D = D_param[col >> 6];
  ushort4 yv = *(ushort4*)(y + i4);
  ushort4 xv = *(const ushort4*)(convo + row * 2304 + col);
  ushort4 zv = *(const ushort4*)(zx + row * 4480 + col);
  float z, s, o[4];
  z = bf2f(zv.x); s = z / (1.0f + expf(-z)); o[0] = (bf2f(yv.x) + D*bf2f(xv.x)) * s;
  z = bf2f(zv.y); s = z / (1.0f + expf(-z)); o[1] = (bf2f(yv.y) + D*bf2f(xv.y)) * s;
  z = bf2f(zv.z); s = z / (1.0f + expf(-z)); o[2] = (bf2f(yv.z) + D*bf2f(xv.z)) * s;
  z = bf2f(zv.w); s = z / (1.0f + expf(-z)); o[3] = (bf2f(yv.w) + D*bf2f(xv.w)) * s;
  *(ushort4*)(y + i4) = make_ushort4(f2bf(o[0]), f2bf(o[1]), f2bf(o[2]), f2bf(o[3]));
}

// ---------------- SwiGLU activation: g = silu(g) * u, in place ----------------
__global__ __launch_bounds__(256) void act_kernel(
    unsigned short* __restrict__ g, const unsigned short* __restrict__ u)
{
  size_t i4 = ((size_t)blockIdx.x * 256 + threadIdx.x) * 4;
  if (i4 >= (size_t)8192 * 4096) return;
  ushort4 gv = *(ushort4*)(g + i4);
  ushort4 uv = *(const ushort4*)(u + i4);
  float x, s, o[4];
  x = bf2f(gv.x); s = x / (1.0f + expf(-x)); o[0] = s * bf2f(uv.x);
  x = bf2f(gv.y); s = x / (1.0f + expf(-x)); o[1] = s * bf2f(uv.y);
  x = bf2f(gv.z); s = x / (1.0f + expf(-x)); o[2] = s * bf2f(uv.z);
  x = bf2f(gv.w); s = x / (1.0f + expf(-x)); o[3] = s * bf2f(uv.w);
  *(ushort4*)(g + i4) = make_ushort4(f2bf(o[0]), f2bf(o[1]), f2bf(o[2]), f2bf(o[3]));
}

// ---------------- workspace arena (bytes) ----------------
static constexpr size_t OFF_RES1 = 0;            // fp32 8192x1024
static constexpr size_t OFF_H1   = 33554432;     // bf16 8192x1024   (h1, then mamba_out)
static constexpr size_t OFF_Y    = 50331648;     // bf16 8192x2048   (y, then gated)
static constexpr size_t OFF_W    = 83886080;     // bf16 weight staging (<= 4480x1024)
static constexpr size_t OFF_ZX   = 93061120;     // bf16 8192x4480   (zxbcdt, then g_out)
static constexpr size_t OFF_CONV = 166461440;    // bf16 8192x2304   (conv_out, then h2)
static constexpr size_t OFF_DTDA = 204210176;    // float2 8192x32 (dt, dA) = 2 MB
static constexpr size_t OFF_U    = 0;            // bf16 8192x4096   (overlaps dead res1/h1/y)

extern "C" void kernel_launch(void* const* d_in, const int* in_sizes, int n_in,
                              void* d_out, int out_size, void* d_ws, size_t ws_size,
                              hipStream_t stream) {
  const float* hid      = (const float*)d_in[0];
  const float* resid    = (const float*)d_in[1];
  const float* ssm_w    = (const float*)d_in[2];
  const float* mlp_w    = (const float*)d_in[3];
  const float* in_proj  = (const float*)d_in[4];
  const float* conv_w   = (const float*)d_in[5];
  const float* conv_b   = (const float*)d_in[6];
  const float* dt_bias  = (const float*)d_in[7];
  const float* A_log    = (const float*)d_in[8];
  const float* D_param  = (const float*)d_in[9];
  const float* out_proj = (const float*)d_in[10];
  const float* gate_w   = (const float*)d_in[11];
  const float* up_w     = (const float*)d_in[12];
  const float* down_w   = (const float*)d_in[13];
  float* out = (float*)d_out;                       // fp32 output: [h | res]
  char* ws = (char*)d_ws;

  float*          res1  = (float*)(ws + OFF_RES1);
  unsigned short* h1    = (unsigned short*)(ws + OFF_H1);
  unsigned short* yb    = (unsigned short*)(ws + OFF_Y);
  unsigned short* Wb    = (unsigned short*)(ws + OFF_W);
  unsigned short* zx    = (unsigned short*)(ws + OFF_ZX);
  unsigned short* convo = (unsigned short*)(ws + OFF_CONV);
  float2*         dtda  = (float2*)(ws + OFF_DTDA);
  unsigned short* ub    = (unsigned short*)(ws + OFF_U);

  rmsnorm1_kernel<<<8192, 256, 0, stream>>>(hid, resid, ssm_w, res1, h1);
  cast_w<<<4480, 256, 0, stream>>>(in_proj, Wb, 4384, 1024, 4480);
  gemm_bt<unsigned short><<<dim3(35, 64), 256, 0, stream>>>(h1, Wb, zx, 8192, 4480, 1024, 4480);
  conv_dt_kernel<<<74752, 256, 0, stream>>>(zx, conv_w, conv_b, dt_bias, A_log,
                                            convo, dtda);
  scan_kernel<<<512, 64, 0, stream>>>(convo, dtda, yb);
  gate_kernel<<<16384, 256, 0, stream>>>(yb, convo, zx, D_param);
  cast_w<<<2048, 256, 0, stream>>>(out_proj, Wb, 1024, 2048, 1024);
  gemm_bt<unsigned short><<<dim3(8, 64), 256, 0, stream>>>(yb, Wb, h1, 8192, 1024, 2048, 1024);
  rmsnorm2_kernel<<<8192, 256, 0, stream>>>(h1, res1, mlp_w, out + 8388608, convo);
  cast_w<<<4096, 256, 0, stream>>>(gate_w, Wb, 4096, 1024, 4096);
  gemm_bt<unsigned short><<<dim3(32, 64), 256, 0, stream>>>(convo, Wb, zx, 8192, 4096, 1024, 4096);
  cast_w<<<4096, 256, 0, stream>>>(up_w, Wb, 4096, 1024, 4096);
  gemm_bt<unsigned short><<<dim3(32, 64), 256, 0, stream>>>(convo, Wb, ub, 8192, 4096, 1024, 4096);
  act_kernel<<<32768, 256, 0, stream>>>(zx, ub);
  cast_w<<<4096, 256, 0, stream>>>(down_w, Wb, 1024, 4096, 1024);
  gemm_bt<float><<<dim3(8, 64), 256, 0, stream>>>(zx, Wb, out, 8192, 1024, 4096, 1024);
}

// Round 6
// 1269.890 us; speedup vs baseline: 1.8352x; 1.3504x over previous
//
#include <hip/hip_runtime.h>

typedef __bf16 bf16x8 __attribute__((ext_vector_type(8)));
typedef float  f32x4  __attribute__((ext_vector_type(4)));

#define GLOAD_LDS16(gp, lp) \
  __builtin_amdgcn_global_load_lds((const __attribute__((address_space(1))) void*)(gp), \
                                   (__attribute__((address_space(3))) void*)(lp), 16, 0, 0)

__device__ __forceinline__ unsigned short f2bf(float f) {
  unsigned u = __float_as_uint(f);
  u += 0x7fffu + ((u >> 16) & 1u);
  return (unsigned short)(u >> 16);
}
__device__ __forceinline__ float bf2f(unsigned short h) {
  return __uint_as_float(((unsigned)h) << 16);
}
__device__ __forceinline__ f32x4 splat4(float v) { f32x4 r = {v, v, v, v}; return r; }

// unpack 4 consecutive bf16 (one uint2-worth packed in two uints) -> f32x4
__device__ __forceinline__ f32x4 up4(unsigned lo, unsigned hi) {
  f32x4 r;
  r[0] = __uint_as_float(lo << 16); r[1] = __uint_as_float(lo & 0xffff0000u);
  r[2] = __uint_as_float(hi << 16); r[3] = __uint_as_float(hi & 0xffff0000u);
  return r;
}
__device__ __forceinline__ unsigned pk2(float a, float b) {
  return (unsigned)f2bf(a) | ((unsigned)f2bf(b) << 16);
}

// 16-lane (DPP row) sum reduction; lane 15 of each row holds the sum.
template <int CTRL>
__device__ __forceinline__ float dpp_add(float v) {
  int t = __builtin_amdgcn_update_dpp(0, __float_as_int(v), CTRL, 0xF, 0xF, true);
  return v + __int_as_float(t);
}
__device__ __forceinline__ float row_sum16(float v) {
  v = dpp_add<0x111>(v);
  v = dpp_add<0x112>(v);
  v = dpp_add<0x114>(v);
  v = dpp_add<0x118>(v);
  return v;
}

__device__ __forceinline__ void store_out(unsigned short* C, size_t idx, float v) {
  C[idx] = f2bf(v);
}
__device__ __forceinline__ void store_out(float* C, size_t idx, float v) {
  C[idx] = v;
}

// ---------------- RMSNorm (prenorm) #1 ----------------
__global__ __launch_bounds__(256) void rmsnorm1_kernel(
    const float* __restrict__ hid, const float* __restrict__ resin,
    const float* __restrict__ w, float* __restrict__ resout,
    unsigned short* __restrict__ hout)
{
  const int row = blockIdx.x, t = threadIdx.x;
  const size_t base = (size_t)row * 1024;
  float4 h = ((const float4*)(hid + base))[t];
  float4 r = ((const float4*)(resin + base))[t];
  float4 s; s.x = h.x + r.x; s.y = h.y + r.y; s.z = h.z + r.z; s.w = h.w + r.w;
  float ss = s.x*s.x + s.y*s.y + s.z*s.z + s.w*s.w;
  #pragma unroll
  for (int off = 32; off; off >>= 1) ss += __shfl_down(ss, off, 64);
  __shared__ float red[4];
  if ((t & 63) == 0) red[t >> 6] = ss;
  __syncthreads();
  float tot = red[0] + red[1] + red[2] + red[3];
  float sc = rsqrtf(tot * (1.0f/1024.0f) + 1e-5f);
  ((float4*)(resout + base))[t] = s;
  float4 wv = ((const float4*)w)[t];
  ushort4 o = make_ushort4(f2bf(s.x*sc*wv.x), f2bf(s.y*sc*wv.y),
                           f2bf(s.z*sc*wv.z), f2bf(s.w*sc*wv.w));
  ((ushort4*)(hout + base))[t] = o;
}

// ---------------- RMSNorm (prenorm) #2 ----------------
__global__ __launch_bounds__(256) void rmsnorm2_kernel(
    const unsigned short* __restrict__ mo, const float* __restrict__ res1,
    const float* __restrict__ w, float* __restrict__ res_out,
    unsigned short* __restrict__ h2)
{
  const int row = blockIdx.x, t = threadIdx.x;
  const size_t base = (size_t)row * 1024;
  float4 r = ((const float4*)(res1 + base))[t];
  ushort4 m = ((const ushort4*)(mo + base))[t];
  float4 s; s.x = r.x + bf2f(m.x); s.y = r.y + bf2f(m.y);
            s.z = r.z + bf2f(m.z); s.w = r.w + bf2f(m.w);
  float ss = s.x*s.x + s.y*s.y + s.z*s.z + s.w*s.w;
  #pragma unroll
  for (int off = 32; off; off >>= 1) ss += __shfl_down(ss, off, 64);
  __shared__ float red[4];
  if ((t & 63) == 0) red[t >> 6] = ss;
  __syncthreads();
  float tot = red[0] + red[1] + red[2] + red[3];
  float sc = rsqrtf(tot * (1.0f/1024.0f) + 1e-5f);
  ((float4*)(res_out + base))[t] = s;
  float4 wv = ((const float4*)w)[t];
  ((ushort4*)(h2 + base))[t] = make_ushort4(f2bf(s.x*sc*wv.x), f2bf(s.y*sc*wv.y),
                                            f2bf(s.z*sc*wv.z), f2bf(s.w*sc*wv.w));
}

// ---------------- fp32 -> bf16 weight cast with row padding ----------------
__global__ __launch_bounds__(256) void cast_w(
    const float* __restrict__ src, unsigned short* __restrict__ dst,
    int rows, int cols, int prows)
{
  size_t i4 = ((size_t)blockIdx.x * 256 + threadIdx.x) * 4;
  size_t total = (size_t)prows * cols;
  if (i4 >= total) return;
  int r = (int)(i4 / cols);
  ushort4 o;
  if (r < rows) {
    float4 v = *(const float4*)(src + i4);
    o = make_ushort4(f2bf(v.x), f2bf(v.y), f2bf(v.z), f2bf(v.w));
  } else {
    o = make_ushort4(0, 0, 0, 0);
  }
  *(ushort4*)(dst + i4) = o;
}

// ---------------- bf16 GEMM (NT), 128x128 tile, mfma 16x16x32 ----------------
template <typename OutT>
__global__ __launch_bounds__(256) void gemm_bt(
    const unsigned short* __restrict__ A, const unsigned short* __restrict__ W,
    OutT* __restrict__ C, int M, int N, int K, int ldc)
{
  __shared__ unsigned short As[128 * 32];
  __shared__ unsigned short Bs[128 * 32];
  const int tid = threadIdx.x;
  const int wave = tid >> 6, lane = tid & 63;
  const int m0 = blockIdx.y << 7, n0 = blockIdx.x << 7;
  const int lr = lane >> 2;
  const int lk = (lane & 3) << 3;
  const int wm = (wave >> 1) << 6, wn = (wave & 1) << 6;
  const int fr = lane & 15, fq = lane >> 4;

  f32x4 acc[4][4];
  #pragma unroll
  for (int i = 0; i < 4; i++)
    #pragma unroll
    for (int j = 0; j < 4; j++)
      #pragma unroll
      for (int r = 0; r < 4; r++) acc[i][j][r] = 0.0f;

  const unsigned short* Abase = A + (size_t)(m0 + wave*32 + lr) * K + lk;
  const unsigned short* Wbase = W + (size_t)(n0 + wave*32 + lr) * K + lk;
  const size_t rstep = (size_t)16 * K;
  unsigned short* AsW = As + (wave*32) * 32;
  unsigned short* BsW = Bs + (wave*32) * 32;

  for (int k0 = 0; k0 < K; k0 += 32) {
    GLOAD_LDS16(Abase + k0,         AsW);
    GLOAD_LDS16(Abase + k0 + rstep, AsW + 16*32);
    GLOAD_LDS16(Wbase + k0,         BsW);
    GLOAD_LDS16(Wbase + k0 + rstep, BsW + 16*32);
    __syncthreads();
    bf16x8 af[4], bfv[4];
    #pragma unroll
    for (int i = 0; i < 4; i++) {
      af[i]  = *(const bf16x8*)(As + (wm + i*16 + fr) * 32 + fq*8);
      bfv[i] = *(const bf16x8*)(Bs + (wn + i*16 + fr) * 32 + fq*8);
    }
    #pragma unroll
    for (int i = 0; i < 4; i++)
      #pragma unroll
      for (int j = 0; j < 4; j++)
        acc[i][j] = __builtin_amdgcn_mfma_f32_16x16x32_bf16(af[i], bfv[j], acc[i][j], 0, 0, 0);
    __syncthreads();
  }

  #pragma unroll
  for (int i = 0; i < 4; i++)
    #pragma unroll
    for (int j = 0; j < 4; j++)
      #pragma unroll
      for (int r = 0; r < 4; r++) {
        int gm = m0 + wm + i*16 + fq*4 + r;
        int gn = n0 + wn + j*16 + fr;
        store_out(C, (size_t)gm * ldc + gn, acc[i][j][r]);
      }
}

// ---------------- causal depthwise conv (K=4) + silu, dt/dA precompute ----------------
__global__ __launch_bounds__(256) void conv_dt_kernel(
    const unsigned short* __restrict__ zx, const float* __restrict__ conv_w,
    const float* __restrict__ conv_b, const float* __restrict__ dt_bias,
    const float* __restrict__ A_log, unsigned short* __restrict__ conv_out,
    float2* __restrict__ dtda)
{
  size_t idx = (size_t)blockIdx.x * 256 + threadIdx.x;
  if (idx >= (size_t)8192 * 2336) return;
  int c = (int)(idx % 2336);
  int row = (int)(idx / 2336);
  int l = row & 4095;
  if (c < 2304) {
    float acc = conv_b[c];
    const float* wp = conv_w + c * 4;
    #pragma unroll
    for (int j = 0; j < 4; j++) {
      int ls = l - 3 + j;
      if (ls >= 0) acc += bf2f(zx[(size_t)(row - 3 + j) * 4480 + 2048 + c]) * wp[j];
    }
    float s = acc / (1.0f + expf(-acc));
    conv_out[(size_t)row * 2304 + c] = f2bf(s);
  } else {
    int h = c - 2304;
    float draw = bf2f(zx[(size_t)row * 4480 + 4352 + h]) + dt_bias[h];
    float sp = (draw > 20.0f) ? draw : log1pf(expf(draw));
    float Ah = -expf(A_log[h]);
    dtda[(size_t)row * 32 + h] = make_float2(sp, expf(sp * Ah));
  }
}

// ============ chunked selective scan ============
// grid 4096 = chunk(8) x oct(8) x h(32) x b(2); 1 wave/wg; no LDS.
// lane: ng=t&15 owns n[8ng..8ng+8); pl=t>>4 owns p pair (pq*8+2pl, +1).
// state: st0/st1 = p-even x n-lo/hi, st2/st3 = p-odd.

// Pass A: local scan from zero state; emit final state (bf16) + chunk decay P.
__global__ __launch_bounds__(64, 4) void scan_passA(
    const unsigned short* __restrict__ convo, const float2* __restrict__ dtda,
    unsigned short* __restrict__ Send, float* __restrict__ Pend)
{
  const int t  = threadIdx.x;
  const int c  = blockIdx.x & 7;
  const int pq = (blockIdx.x >> 3) & 7;
  const int h  = (blockIdx.x >> 6) & 31;
  const int b  = blockIdx.x >> 11;
  const int ng = t & 15, pl = t >> 4;
  const size_t row0 = (size_t)b * 4096 + (size_t)c * 512;
  const unsigned short* Bp = convo + row0 * 2304 + 2048 + ng * 8;
  const unsigned short* Xp = convo + row0 * 2304 + h * 64 + pq * 8 + pl * 2;
  const float2* Dp = dtda + row0 * 32 + h;

  f32x4 st0 = splat4(0.f), st1 = splat4(0.f), st2 = splat4(0.f), st3 = splat4(0.f);
  float P = 1.0f;
  uint4 Bv[2][4]; unsigned xv[2][4]; float2 dd[2][4];

  auto ld = [&](int set, int g) {
    #pragma unroll
    for (int s = 0; s < 4; s++) {
      size_t r = (size_t)(g * 4 + s);
      Bv[set][s] = *(const uint4*)(Bp + r * 2304);
      xv[set][s] = *(const unsigned*)(Xp + r * 2304);
      dd[set][s] = Dp[r * 32];
    }
  };
  auto comp = [&](int set) {
    #pragma unroll
    for (int s = 0; s < 4; s++) {
      float dt = dd[set][s].x, dA = dd[set][s].y;
      unsigned xw = xv[set][s];
      float u0 = dt * __uint_as_float(xw << 16);
      float u1 = dt * __uint_as_float(xw & 0xffff0000u);
      uint4 r = Bv[set][s];
      f32x4 B0 = up4(r.x, r.y), B1 = up4(r.z, r.w);
      f32x4 dAv = splat4(dA);
      st0 = st0 * dAv + B0 * splat4(u0);
      st1 = st1 * dAv + B1 * splat4(u0);
      st2 = st2 * dAv + B0 * splat4(u1);
      st3 = st3 * dAv + B1 * splat4(u1);
      P *= dA;
    }
  };

  ld(0, 0);
  for (int g = 0; g < 128; g += 2) {
    ld(1, g + 1);
    comp(0);
    if (g + 2 < 128) ld(0, g + 2);
    comp(1);
  }

  unsigned w0 = pk2(st0[0], st0[1]), w1 = pk2(st0[2], st0[3]);
  unsigned w2 = pk2(st1[0], st1[1]), w3 = pk2(st1[2], st1[3]);
  unsigned w4 = pk2(st2[0], st2[1]), w5 = pk2(st2[2], st2[3]);
  unsigned w6 = pk2(st3[0], st3[1]), w7 = pk2(st3[2], st3[3]);
  size_t slot = ((((size_t)(b * 32 + h) * 8 + c) * 8 + pq) * 64 + t) * 16;
  *(uint4*)(Send + slot)     = make_uint4(w0, w1, w2, w3);
  *(uint4*)(Send + slot + 8) = make_uint4(w4, w5, w6, w7);
  if (t == 0) Pend[(b * 32 + h) * 8 + c] = P;
}

// Combine: sequential over 8 chunks; in-place transform Send -> Sstart.
__global__ __launch_bounds__(64) void scan_combine(
    unsigned short* __restrict__ S, const float* __restrict__ Pend)
{
  const int t  = threadIdx.x;
  const int pq = blockIdx.x & 7;
  const int h  = (blockIdx.x >> 3) & 31;
  const int b  = blockIdx.x >> 8;
  const int bh = b * 32 + h;
  f32x4 r0 = splat4(0.f), r1 = splat4(0.f), r2 = splat4(0.f), r3 = splat4(0.f);
  for (int c = 0; c < 8; c++) {
    size_t slot = ((((size_t)bh * 8 + c) * 8 + pq) * 64 + t) * 16;
    uint4 a = *(const uint4*)(S + slot);
    uint4 bq = *(const uint4*)(S + slot + 8);
    float P = Pend[bh * 8 + c];
    // write Sstart(c) = running
    *(uint4*)(S + slot) = make_uint4(pk2(r0[0], r0[1]), pk2(r0[2], r0[3]),
                                     pk2(r1[0], r1[1]), pk2(r1[2], r1[3]));
    *(uint4*)(S + slot + 8) = make_uint4(pk2(r2[0], r2[1]), pk2(r2[2], r2[3]),
                                         pk2(r3[0], r3[1]), pk2(r3[2], r3[3]));
    f32x4 Pv = splat4(P);
    r0 = up4(a.x, a.y)  + Pv * r0;
    r1 = up4(a.z, a.w)  + Pv * r1;
    r2 = up4(bq.x, bq.y) + Pv * r2;
    r3 = up4(bq.z, bq.w) + Pv * r3;
  }
}

// Pass B: full scan per chunk seeded with Sstart; emit y.
__global__ __launch_bounds__(64, 4) void scan_passB(
    const unsigned short* __restrict__ convo, const float2* __restrict__ dtda,
    const unsigned short* __restrict__ Sstart, unsigned short* __restrict__ y)
{
  const int t  = threadIdx.x;
  const int c  = blockIdx.x & 7;
  const int pq = (blockIdx.x >> 3) & 7;
  const int h  = (blockIdx.x >> 6) & 31;
  const int b  = blockIdx.x >> 11;
  const int ng = t & 15, pl = t >> 4;
  const size_t row0 = (size_t)b * 4096 + (size_t)c * 512;
  const unsigned short* Bp = convo + row0 * 2304 + 2048 + ng * 8;
  const unsigned short* Cp = convo + row0 * 2304 + 2176 + ng * 8;
  const unsigned short* Xp = convo + row0 * 2304 + h * 64 + pq * 8 + pl * 2;
  const float2* Dp = dtda + row0 * 32 + h;

  size_t slot = ((((size_t)(b * 32 + h) * 8 + c) * 8 + pq) * 64 + t) * 16;
  uint4 sa = *(const uint4*)(Sstart + slot);
  uint4 sb = *(const uint4*)(Sstart + slot + 8);
  f32x4 st0 = up4(sa.x, sa.y), st1 = up4(sa.z, sa.w);
  f32x4 st2 = up4(sb.x, sb.y), st3 = up4(sb.z, sb.w);

  uint4 Bv[2][4], Cv[2][4]; unsigned xv[2][4]; float2 dd[2][4];

  auto ld = [&](int set, int g) {
    #pragma unroll
    for (int s = 0; s < 4; s++) {
      size_t r = (size_t)(g * 4 + s);
      Bv[set][s] = *(const uint4*)(Bp + r * 2304);
      Cv[set][s] = *(const uint4*)(Cp + r * 2304);
      xv[set][s] = *(const unsigned*)(Xp + r * 2304);
      dd[set][s] = Dp[r * 32];
    }
  };
  auto comp = [&](int set, int g) {
    #pragma unroll
    for (int s = 0; s < 4; s++) {
      float dt = dd[set][s].x, dA = dd[set][s].y;
      unsigned xw = xv[set][s];
      float u0 = dt * __uint_as_float(xw << 16);
      float u1 = dt * __uint_as_float(xw & 0xffff0000u);
      uint4 r = Bv[set][s];
      f32x4 B0 = up4(r.x, r.y), B1 = up4(r.z, r.w);
      uint4 q = Cv[set][s];
      f32x4 C0 = up4(q.x, q.y), C1 = up4(q.z, q.w);
      f32x4 dAv = splat4(dA);
      st0 = st0 * dAv + B0 * splat4(u0);
      st1 = st1 * dAv + B1 * splat4(u0);
      st2 = st2 * dAv + B0 * splat4(u1);
      st3 = st3 * dAv + B1 * splat4(u1);
      f32x4 a0v = st0 * C0 + st1 * C1;
      f32x4 a1v = st2 * C0 + st3 * C1;
      float a0 = (a0v[0] + a0v[2]) + (a0v[1] + a0v[3]);
      float a1 = (a1v[0] + a1v[2]) + (a1v[1] + a1v[3]);
      a0 = row_sum16(a0);
      a1 = row_sum16(a1);
      if (ng == 15) {
        size_t row = row0 + (size_t)(g * 4 + s);
        ((unsigned*)y)[row * 1024 + h * 32 + pq * 4 + pl] = pk2(a0, a1);
      }
    }
  };

  ld(0, 0);
  for (int g = 0; g < 128; g += 2) {
    ld(1, g + 1);
    comp(0, g);
    if (g + 2 < 128) ld(0, g + 2);
    comp(1, g + 1);
  }
}

// ---------------- gating: y = (y + D[h]*xh) * silu(z), in place ----------------
__global__ __launch_bounds__(256) void gate_kernel(
    unsigned short* __restrict__ y, const unsigned short* __restrict__ convo,
    const unsigned short* __restrict__ zx, const float* __restrict__ D_param)
{
  size_t i4 = ((size_t)blockIdx.x * 256 + threadIdx.x) * 4;
  if (i4 >= (size_t)8192 * 2048) return;
  int col = (int)(i4 % 2048);
  size_t row = i4 / 2048;
  float D = D_param[col >> 6];
  ushort4 yv = *(ushort4*)(y + i4);
  ushort4 xv = *(const ushort4*)(convo + row * 2304 + col);
  ushort4 zv = *(const ushort4*)(zx + row * 4480 + col);
  float z, s, o[4];
  z = bf2f(zv.x); s = z / (1.0f + expf(-z)); o[0] = (bf2f(yv.x) + D*bf2f(xv.x)) * s;
  z = bf2f(zv.y); s = z / (1.0f + expf(-z)); o[1] = (bf2f(yv.y) + D*bf2f(xv.y)) * s;
  z = bf2f(zv.z); s = z / (1.0f + expf(-z)); o[2] = (bf2f(yv.z) + D*bf2f(xv.z)) * s;
  z = bf2f(zv.w); s = z / (1.0f + expf(-z)); o[3] = (bf2f(yv.w) + D*bf2f(xv.w)) * s;
  *(ushort4*)(y + i4) = make_ushort4(f2bf(o[0]), f2bf(o[1]), f2bf(o[2]), f2bf(o[3]));
}

// ---------------- SwiGLU activation: g = silu(g) * u, in place ----------------
__global__ __launch_bounds__(256) void act_kernel(
    unsigned short* __restrict__ g, const unsigned short* __restrict__ u)
{
  size_t i4 = ((size_t)blockIdx.x * 256 + threadIdx.x) * 4;
  if (i4 >= (size_t)8192 * 4096) return;
  ushort4 gv = *(ushort4*)(g + i4);
  ushort4 uv = *(const ushort4*)(u + i4);
  float x, s, o[4];
  x = bf2f(gv.x); s = x / (1.0f + expf(-x)); o[0] = s * bf2f(uv.x);
  x = bf2f(gv.y); s = x / (1.0f + expf(-x)); o[1] = s * bf2f(uv.y);
  x = bf2f(gv.z); s = x / (1.0f + expf(-x)); o[2] = s * bf2f(uv.z);
  x = bf2f(gv.w); s = x / (1.0f + expf(-x)); o[3] = s * bf2f(uv.w);
  *(ushort4*)(g + i4) = make_ushort4(f2bf(o[0]), f2bf(o[1]), f2bf(o[2]), f2bf(o[3]));
}

// ---------------- workspace arena (bytes) ----------------
static constexpr size_t OFF_RES1 = 0;            // fp32 8192x1024
static constexpr size_t OFF_H1   = 33554432;     // bf16 8192x1024 (h1; then Send/Sstart 16.78MB; then mamba_out)
static constexpr size_t OFF_Y    = 50331648;     // bf16 8192x2048   (y, then gated)
static constexpr size_t OFF_W    = 83886080;     // bf16 weight staging (also Pend during scan)
static constexpr size_t OFF_ZX   = 93061120;     // bf16 8192x4480   (zxbcdt, then g_out)
static constexpr size_t OFF_CONV = 166461440;    // bf16 8192x2304   (conv_out, then h2)
static constexpr size_t OFF_DTDA = 204210176;    // float2 8192x32 (dt, dA) = 2 MB
static constexpr size_t OFF_U    = 0;            // bf16 8192x4096   (overlaps dead res1/h1/y)

extern "C" void kernel_launch(void* const* d_in, const int* in_sizes, int n_in,
                              void* d_out, int out_size, void* d_ws, size_t ws_size,
                              hipStream_t stream) {
  const float* hid      = (const float*)d_in[0];
  const float* resid    = (const float*)d_in[1];
  const float* ssm_w    = (const float*)d_in[2];
  const float* mlp_w    = (const float*)d_in[3];
  const float* in_proj  = (const float*)d_in[4];
  const float* conv_w   = (const float*)d_in[5];
  const float* conv_b   = (const float*)d_in[6];
  const float* dt_bias  = (const float*)d_in[7];
  const float* A_log    = (const float*)d_in[8];
  const float* D_param  = (const float*)d_in[9];
  const float* out_proj = (const float*)d_in[10];
  const float* gate_w   = (const float*)d_in[11];
  const float* up_w     = (const float*)d_in[12];
  const float* down_w   = (const float*)d_in[13];
  float* out = (float*)d_out;                       // fp32 output: [h | res]
  char* ws = (char*)d_ws;

  float*          res1  = (float*)(ws + OFF_RES1);
  unsigned short* h1    = (unsigned short*)(ws + OFF_H1);   // h1 / Send / mamba_out
  unsigned short* yb    = (unsigned short*)(ws + OFF_Y);
  unsigned short* Wb    = (unsigned short*)(ws + OFF_W);
  unsigned short* zx    = (unsigned short*)(ws + OFF_ZX);
  unsigned short* convo = (unsigned short*)(ws + OFF_CONV);
  float2*         dtda  = (float2*)(ws + OFF_DTDA);
  unsigned short* ub    = (unsigned short*)(ws + OFF_U);
  float*          Pend  = (float*)(ws + OFF_W);             // 8KB, Wb dead during scan

  rmsnorm1_kernel<<<8192, 256, 0, stream>>>(hid, resid, ssm_w, res1, h1);
  cast_w<<<4480, 256, 0, stream>>>(in_proj, Wb, 4384, 1024, 4480);
  gemm_bt<unsigned short><<<dim3(35, 64), 256, 0, stream>>>(h1, Wb, zx, 8192, 4480, 1024, 4480);
  conv_dt_kernel<<<74752, 256, 0, stream>>>(zx, conv_w, conv_b, dt_bias, A_log,
                                            convo, dtda);
  // chunked scan: h1 buffer (dead here) holds Send -> Sstart (exactly 16.78 MB)
  scan_passA<<<4096, 64, 0, stream>>>(convo, dtda, h1, Pend);
  scan_combine<<<512, 64, 0, stream>>>(h1, Pend);
  scan_passB<<<4096, 64, 0, stream>>>(convo, dtda, h1, yb);
  gate_kernel<<<16384, 256, 0, stream>>>(yb, convo, zx, D_param);
  cast_w<<<2048, 256, 0, stream>>>(out_proj, Wb, 1024, 2048, 1024);
  gemm_bt<unsigned short><<<dim3(8, 64), 256, 0, stream>>>(yb, Wb, h1, 8192, 1024, 2048, 1024);
  rmsnorm2_kernel<<<8192, 256, 0, stream>>>(h1, res1, mlp_w, out + 8388608, convo);
  cast_w<<<4096, 256, 0, stream>>>(gate_w, Wb, 4096, 1024, 4096);
  gemm_bt<unsigned short><<<dim3(32, 64), 256, 0, stream>>>(convo, Wb, zx, 8192, 4096, 1024, 4096);
  cast_w<<<4096, 256, 0, stream>>>(up_w, Wb, 4096, 1024, 4096);
  gemm_bt<unsigned short><<<dim3(32, 64), 256, 0, stream>>>(convo, Wb, ub, 8192, 4096, 1024, 4096);
  act_kernel<<<32768, 256, 0, stream>>>(zx, ub);
  cast_w<<<4096, 256, 0, stream>>>(down_w, Wb, 1024, 4096, 1024);
  gemm_bt<float><<<dim3(8, 64), 256, 0, stream>>>(zx, Wb, out, 8192, 1024, 4096, 1024);
}